// Round 4
// baseline (1729.347 us; speedup 1.0000x reference)
//
#include <hip/hip_runtime.h>
#include <hip/hip_bf16.h>

typedef unsigned short u16;
typedef __bf16 bf16x8 __attribute__((ext_vector_type(8)));
typedef unsigned short u16x8 __attribute__((ext_vector_type(8)));
typedef unsigned short u16x4 __attribute__((ext_vector_type(4)));
typedef float f32x4 __attribute__((ext_vector_type(4)));

#define DI static __device__ __forceinline__

DI u16 f2bf(float f) {
    unsigned u = __builtin_bit_cast(unsigned, f);
    u += 0x7FFFu + ((u >> 16) & 1u);   // round-to-nearest-even
    return (u16)(u >> 16);
}
DI float bf2f(u16 u) {
    unsigned x = ((unsigned)u) << 16;
    return __builtin_bit_cast(float, x);
}
DI u16x8 ld8_f32(const float* __restrict__ p) {
    const float4 a = *(const float4*)p;
    const float4 b = *(const float4*)(p + 4);
    u16x8 r = { f2bf(a.x), f2bf(a.y), f2bf(a.z), f2bf(a.w),
                f2bf(b.x), f2bf(b.y), f2bf(b.z), f2bf(b.w) };
    return r;
}
DI f32x4 mfma16(u16x8 a, u16x8 b, f32x4 c) {
    return __builtin_amdgcn_mfma_f32_16x16x32_bf16(
        __builtin_bit_cast(bf16x8, a), __builtin_bit_cast(bf16x8, b), c, 0, 0, 0);
}

// ---------------------------------------------------------------- cast ----
__global__ void __launch_bounds__(256) k_cast(const float* __restrict__ in,
                                              u16* __restrict__ out, long n4) {
    long i = (long)blockIdx.x * 256 + threadIdx.x;
    if (i >= n4) return;
    const float4 v = *(const float4*)(in + i * 4);
    u16x4 o = { f2bf(v.x), f2bf(v.y), f2bf(v.z), f2bf(v.w) };
    *(u16x4*)(out + i * 4) = o;
}

// ---------------------------------------------------------------- GEMM ----
// C[M,N] = alpha*A[M,K]*B[N,K]^T (+bias[n]) (+C-accum) (+relu).
// A/B may be fp32 (converted during LDS staging) or bf16. fp32 accumulate.
// 128x128 tile, BK=64, 4 waves (2x2), wave = 64x64 = 4x4 frags of 16x16x32.
template <int AF32, int BF32>
__global__ void __launch_bounds__(256) k_gemm_bt(
    const void* __restrict__ Ap, long lda,
    const void* __restrict__ Bp, long ldb,
    float* __restrict__ Cf, u16* __restrict__ Cb, long ldc,
    const float* __restrict__ bias, int relu, int accum, float alpha, int K,
    int Hdiv, long sAb, long sAh, long sBb, long sBh, long sCb, long sCh)
{
    __shared__ __align__(16) u16 As[128 * 72];
    __shared__ __align__(16) u16 Bs[128 * 72];
    const int tid  = threadIdx.x;
    const int lane = tid & 63, wave = tid >> 6;
    const int r16  = lane & 15, quad = lane >> 4;
    const int wr   = (wave >> 1) * 64, wc = (wave & 1) * 64;
    const int zb = blockIdx.z / Hdiv, zh = blockIdx.z % Hdiv;
    const long aoff = (long)zb * sAb + (long)zh * sAh + (long)blockIdx.x * 128 * lda;
    const long boff = (long)zb * sBb + (long)zh * sBh + (long)blockIdx.y * 128 * ldb;
    const u16*   A16 = (const u16*)Ap + aoff;
    const float* A32 = (const float*)Ap + aoff;
    const u16*   B16 = (const u16*)Bp + boff;
    const float* B32 = (const float*)Bp + boff;
    const long coff = (long)zb * sCb + (long)zh * sCh +
                      (long)blockIdx.x * 128 * ldc + (long)blockIdx.y * 128;

    f32x4 acc[4][4];
#pragma unroll
    for (int i = 0; i < 4; i++)
#pragma unroll
        for (int j = 0; j < 4; j++) acc[i][j] = f32x4{0.f, 0.f, 0.f, 0.f};

    const int st_row = tid >> 3;          // 0..31, +32*r
    const int st_col = (tid & 7) * 8;     // 0..56

    for (int k0 = 0; k0 < K; k0 += 64) {
#pragma unroll
        for (int r = 0; r < 4; r++) {
            const int row = st_row + 32 * r;
            if constexpr (AF32)
                *(u16x8*)(As + row * 72 + st_col) = ld8_f32(A32 + (long)row * lda + k0 + st_col);
            else
                *(uint4*)(As + row * 72 + st_col) = *(const uint4*)(A16 + (long)row * lda + k0 + st_col);
            if constexpr (BF32)
                *(u16x8*)(Bs + row * 72 + st_col) = ld8_f32(B32 + (long)row * ldb + k0 + st_col);
            else
                *(uint4*)(Bs + row * 72 + st_col) = *(const uint4*)(B16 + (long)row * ldb + k0 + st_col);
        }
        __syncthreads();
#pragma unroll
        for (int kk = 0; kk < 64; kk += 32) {
            u16x8 af[4], bfr[4];
#pragma unroll
            for (int i = 0; i < 4; i++)
                af[i] = *(const u16x8*)(As + (wr + i * 16 + r16) * 72 + kk + 8 * quad);
#pragma unroll
            for (int j = 0; j < 4; j++)
                bfr[j] = *(const u16x8*)(Bs + (wc + j * 16 + r16) * 72 + kk + 8 * quad);
#pragma unroll
            for (int i = 0; i < 4; i++)
#pragma unroll
                for (int j = 0; j < 4; j++)
                    acc[i][j] = mfma16(af[i], bfr[j], acc[i][j]);
        }
        __syncthreads();
    }

#pragma unroll
    for (int i = 0; i < 4; i++) {
#pragma unroll
        for (int j = 0; j < 4; j++) {
            const int gcol = wc + j * 16 + r16;
            const float bv = bias ? bias[blockIdx.y * 128 + gcol] : 0.f;
#pragma unroll
            for (int r = 0; r < 4; r++) {
                const long o = coff + (long)(wr + i * 16 + quad * 4 + r) * ldc + gcol;
                float v = acc[i][j][r] * alpha + bv;
                if (accum) v += Cf[o];
                if (relu) v = fmaxf(v, 0.f);
                if (Cf) Cf[o] = v;
                if (Cb) Cb[o] = f2bf(v);
            }
        }
    }
}

// ----------------------------------------------------- fused attention ----
// grid (T/64, H, B), 256 thr = 4 waves; wave owns 16 q-rows, DH=256.
// K tile [32 kv][256 d] (stride 264); V^T tile [256 d][32 kv] (stride 40,
// from globally pre-transposed Vt) so the PV B-fragment is one ds_read_b128.
// Async-STAGE (T14): next tile's global loads issued before compute, LDS
// written after the post-compute barrier. __launch_bounds__(256,2) caps
// VGPR at 256 so the staging registers do NOT spill to scratch (R3 bug:
// default bounds -> 120 VGPR + ~700MB scratch writes per dispatch).
template <int MASKED>
__global__ void __launch_bounds__(256, 2) k_attn(
    const u16* __restrict__ Q, const u16* __restrict__ Kg, const u16* __restrict__ Vt,
    u16* __restrict__ O, int T, float scale)
{
    const int D = 1024;
    __shared__ __align__(16) u16 Ks[32 * 264];
    __shared__ __align__(16) u16 VsT[256 * 40];
    __shared__ __align__(16) u16 Ps[4][16 * 40];
    const int tid = threadIdx.x, lane = tid & 63, wave = tid >> 6;
    const int r16 = lane & 15, quad = lane >> 4;
    const long base   = ((long)blockIdx.z * T) * D + blockIdx.y * 256;
    const long vtbase = ((long)(blockIdx.z * 4 + blockIdx.y) * 256) * 2048;
    const int qr0 = blockIdx.x * 64 + wave * 16;

    u16x8 qf[8];
#pragma unroll
    for (int ks = 0; ks < 8; ks++)
        qf[ks] = *(const u16x8*)(Q + base + (long)(qr0 + r16) * D + ks * 32 + 8 * quad);

    f32x4 oacc[16];
#pragma unroll
    for (int nt = 0; nt < 16; nt++) oacc[nt] = f32x4{0.f, 0.f, 0.f, 0.f};
    float mrun[4] = {-1e30f, -1e30f, -1e30f, -1e30f};
    float lrun[4] = {0.f, 0.f, 0.f, 0.f};

    // K staging map: rows 32 x cols 256
    const int krow = tid >> 5, kcol = (tid & 31) * 8;   // +8*r rows
    // V^T staging map: rows 256 (d) x cols 32 (kv)
    const int vrow = tid >> 2, vcol = (tid & 3) * 8;    // +64*r rows
    const int nkb = MASKED ? (blockIdx.x * 2 + 2) : (T / 32);

    uint4 kreg[4], vreg[4];
    auto stage_regs = [&](int kb) {
#pragma unroll
        for (int r = 0; r < 4; r++)
            kreg[r] = *(const uint4*)(Kg + base + (long)(kb * 32 + krow + 8 * r) * D + kcol);
#pragma unroll
        for (int r = 0; r < 4; r++)
            vreg[r] = *(const uint4*)(Vt + vtbase + (long)(vrow + 64 * r) * 2048 + kb * 32 + vcol);
    };
    auto write_lds = [&]() {
#pragma unroll
        for (int r = 0; r < 4; r++)
            *(uint4*)(Ks + (krow + 8 * r) * 264 + kcol) = kreg[r];
#pragma unroll
        for (int r = 0; r < 4; r++)
            *(uint4*)(VsT + (vrow + 64 * r) * 40 + vcol) = vreg[r];
    };

    stage_regs(0);
    write_lds();

    for (int kb = 0; kb < nkb; kb++) {
        __syncthreads();                       // LDS[kb] visible to all
        if (kb + 1 < nkb) stage_regs(kb + 1);  // overlap HBM with compute

        // ---- S = Q K^T (two 16-key halves) ----
        f32x4 s0 = f32x4{0.f,0.f,0.f,0.f}, s1 = f32x4{0.f,0.f,0.f,0.f};
#pragma unroll
        for (int ks = 0; ks < 8; ks++) {
            s0 = mfma16(qf[ks], *(const u16x8*)(Ks + (r16)      * 264 + ks * 32 + 8 * quad), s0);
            s1 = mfma16(qf[ks], *(const u16x8*)(Ks + (16 + r16) * 264 + ks * 32 + 8 * quad), s1);
        }

        // ---- online softmax (16-lane groups) ----
        float p[2][4], al[4];
#pragma unroll
        for (int r = 0; r < 4; r++) {
            float a0 = s0[r] * scale, a1 = s1[r] * scale;
            if (MASKED) {
                const int qi = qr0 + quad * 4 + r;
                if (kb * 32 + r16 > qi)      a0 = -1e30f;
                if (kb * 32 + 16 + r16 > qi) a1 = -1e30f;
            }
            float bm = fmaxf(a0, a1);
#pragma unroll
            for (int m = 1; m < 16; m <<= 1) bm = fmaxf(bm, __shfl_xor(bm, m));
            const float mn = fmaxf(mrun[r], bm);
            al[r] = __expf(mrun[r] - mn);
            const float p0 = __expf(a0 - mn), p1 = __expf(a1 - mn);
            float rs = p0 + p1;
#pragma unroll
            for (int m = 1; m < 16; m <<= 1) rs += __shfl_xor(rs, m);
            lrun[r] = lrun[r] * al[r] + rs;
            mrun[r] = mn;
            p[0][r] = p0; p[1][r] = p1;
        }

        // ---- P -> bf16 via wave-private LDS (A-fragment layout) ----
        u16* pw = &Ps[wave][0];
#pragma unroll
        for (int r = 0; r < 4; r++) {
            pw[(quad * 4 + r) * 40 + r16]      = f2bf(p[0][r]);
            pw[(quad * 4 + r) * 40 + 16 + r16] = f2bf(p[1][r]);
        }
#pragma unroll
        for (int nt = 0; nt < 16; nt++) {
            oacc[nt][0] *= al[0]; oacc[nt][1] *= al[1];
            oacc[nt][2] *= al[2]; oacc[nt][3] *= al[3];
        }
        const u16x8 pf = *(const u16x8*)(pw + r16 * 40 + 8 * quad);

        // ---- O += P V : B-fragment = one b128 from V^T ----
#pragma unroll
        for (int nt = 0; nt < 16; nt++) {
            const u16x8 vf = *(const u16x8*)(VsT + (nt * 16 + r16) * 40 + 8 * quad);
            oacc[nt] = mfma16(pf, vf, oacc[nt]);
        }

        __syncthreads();                       // all waves done reading LDS[kb]
        if (kb + 1 < nkb) write_lds();
    }

#pragma unroll
    for (int nt = 0; nt < 16; nt++)
#pragma unroll
        for (int r = 0; r < 4; r++)
            O[base + (long)(qr0 + quad * 4 + r) * D + nt * 16 + r16] =
                f2bf(oacc[nt][r] / lrun[r]);
}

// ----------------------------------------------------- add + layernorm ----
template <int XF32, int RF32>
__global__ void __launch_bounds__(256) k_addln(
    const void* __restrict__ Xp, const void* __restrict__ Rp,
    const float* __restrict__ G, const float* __restrict__ Bv,
    float* __restrict__ Yf, u16* __restrict__ Yb)
{
    const int tid = threadIdx.x;
    const long off = (long)blockIdx.x * 1024 + tid * 4;
    float v[4];
    if constexpr (XF32) {
        const float4 a = *(const float4*)((const float*)Xp + off);
        v[0] = a.x; v[1] = a.y; v[2] = a.z; v[3] = a.w;
    } else {
        const u16x4 a = *(const u16x4*)((const u16*)Xp + off);
        v[0] = bf2f(a[0]); v[1] = bf2f(a[1]); v[2] = bf2f(a[2]); v[3] = bf2f(a[3]);
    }
    if constexpr (RF32) {
        const float4 b = *(const float4*)((const float*)Rp + off);
        v[0] += b.x; v[1] += b.y; v[2] += b.z; v[3] += b.w;
    } else {
        const u16x4 b = *(const u16x4*)((const u16*)Rp + off);
        v[0] += bf2f(b[0]); v[1] += bf2f(b[1]); v[2] += bf2f(b[2]); v[3] += bf2f(b[3]);
    }
    float s1 = v[0] + v[1] + v[2] + v[3];
    float s2 = v[0]*v[0] + v[1]*v[1] + v[2]*v[2] + v[3]*v[3];
#pragma unroll
    for (int m = 1; m < 64; m <<= 1) { s1 += __shfl_xor(s1, m); s2 += __shfl_xor(s2, m); }
    __shared__ float red[8];
    if ((tid & 63) == 0) { red[(tid >> 6) * 2] = s1; red[(tid >> 6) * 2 + 1] = s2; }
    __syncthreads();
    s1 = red[0] + red[2] + red[4] + red[6];
    s2 = red[1] + red[3] + red[5] + red[7];
    const float mean = s1 * (1.f / 1024.f);
    const float rstd = rsqrtf(s2 * (1.f / 1024.f) - mean * mean + 1e-5f);
    const float4 g  = *(const float4*)(G + tid * 4);
    const float4 be = *(const float4*)(Bv + tid * 4);
    const float o0 = (v[0] - mean) * rstd * g.x + be.x;
    const float o1 = (v[1] - mean) * rstd * g.y + be.y;
    const float o2 = (v[2] - mean) * rstd * g.z + be.z;
    const float o3 = (v[3] - mean) * rstd * g.w + be.w;
    if (Yf) { float4 of = {o0, o1, o2, o3}; *(float4*)(Yf + off) = of; }
    if (Yb) { u16x4 ob = {f2bf(o0), f2bf(o1), f2bf(o2), f2bf(o3)}; *(u16x4*)(Yb + off) = ob; }
}

// -------------------------------------------- per-(b,h) head transpose ----
// X[(b*2048+t)*1024 + h*256 + e] -> Y[(bh*256 + e)*2048 + t]
__global__ void __launch_bounds__(256) k_transpose(const u16* __restrict__ Xin,
                                                   u16* __restrict__ Y)
{
    __shared__ u16 tile[32][33];
    const int tx = threadIdx.x & 31, ty = threadIdx.x >> 5;
    const int t0 = blockIdx.x * 32, e0 = blockIdx.y * 32, bh = blockIdx.z;
    const int b = bh >> 2, h = bh & 3;
#pragma unroll
    for (int i = 0; i < 4; i++)
        tile[ty + 8 * i][tx] =
            Xin[((long)(b * 2048 + t0 + ty + 8 * i)) * 1024 + h * 256 + e0 + tx];
    __syncthreads();
#pragma unroll
    for (int i = 0; i < 4; i++)
        Y[((long)bh * 256 + e0 + ty + 8 * i) * 2048 + t0 + tx] = tile[tx][ty + 8 * i];
}

// ------------------------------------------------------------- driver ----
#define GEMM(AF, BF, Aptr, lda, Bptr, ldb, pCf, pCb, ldc, bias, relu, accum, alpha, \
             M, N, K, Z, Hdiv, sAb, sAh, sBb, sBh, sCb, sCh)                        \
    k_gemm_bt<AF, BF><<<dim3((M) / 128, (N) / 128, (Z)), dim3(256), 0, stream>>>(   \
        (const void*)(Aptr), (lda), (const void*)(Bptr), (ldb), (pCf), (pCb),       \
        (ldc), (bias), (relu), (accum), (alpha), (K), (Hdiv),                       \
        (long)(sAb), (long)(sAh), (long)(sBb), (long)(sBh), (long)(sCb), (long)(sCh))

extern "C" void kernel_launch(void* const* d_in, const int* in_sizes, int n_in,
                              void* d_out, int out_size, void* d_ws, size_t ws_size,
                              hipStream_t stream)
{
    const int Bn = 4, T = 2048, D = 1024, H = 4, DH = 256;
    const long BTD = (long)Bn * T * D;           // 8388608 elems
    const long MB = 1024 * 1024;

    const float* ctx = (const float*)d_in[0];
    const float* X   = (const float*)d_in[1];
    const float* Wh[9]; for (int i = 0; i < 9; i++) Wh[i] = (const float*)d_in[2 + i];
    const float* dec_w1 = (const float*)d_in[11]; const float* dec_b1 = (const float*)d_in[12];
    const float* dec_w2 = (const float*)d_in[13]; const float* dec_b2 = (const float*)d_in[14];
    const float* enc_w1 = (const float*)d_in[15]; const float* enc_b1 = (const float*)d_in[16];
    const float* enc_w2 = (const float*)d_in[17]; const float* enc_b2 = (const float*)d_in[18];
    const float* ln[10]; for (int i = 0; i < 10; i++) ln[i] = (const float*)d_in[19 + i];
    (void)in_sizes; (void)n_in; (void)out_size;

    float* outC = (float*)d_out;        // c  [B,T,D] fp32
    float* outY = (float*)d_out + BTD;  // out[B,T,D] fp32

    // ---- workspace pool (98.3 MB core) ----
    char* w = (char*)d_ws;
    u16*   qb   = (u16*)(w);                 // 16 MB
    u16*   kb   = (u16*)(w + 16 * MB);       // 16 MB
    u16*   vb   = (u16*)(w + 32 * MB);       // 16 MB (V proj; then attn out)
    u16*   tmpB = (u16*)(w + 48 * MB);       // 16 MB (V^T for attn; cross out)
    u16*   hb   = (u16*)(w);                 // 16 MB (FFN hidden chunk)
    float* tmpF = (float*)(w + 32 * MB);     // 32 MB (FFN fp32 accum)
    u16*   Vt   = (u16*)(w + 32 * MB);       // 16 MB (cross V^T)
    u16*   Kt   = (u16*)(w + 48 * MB);       // 16 MB (cross K^T)
    u16*   Nm   = (u16*)(w + 64 * MB);       //  2 MB
    u16*   x1b  = (u16*)(w + 66 * MB);       // 16 MB
    u16*   t2b  = (u16*)(w + 82 * MB);       // 16 MB (c1, then x2)
    const bool wcast = ws_size >= 140 * (size_t)MB;
    u16* w1eb = (u16*)(w + 98 * MB);  u16* w2eb = (u16*)(w + 106 * MB);
    u16* w1db = (u16*)(w + 114 * MB); u16* w2db = (u16*)(w + 122 * MB);

    if (wcast) {
        k_cast<<<dim3(4096), dim3(256), 0, stream>>>(enc_w1, w1eb, 1048576);
        k_cast<<<dim3(4096), dim3(256), 0, stream>>>(enc_w2, w2eb, 1048576);
        k_cast<<<dim3(4096), dim3(256), 0, stream>>>(dec_w1, w1db, 1048576);
        k_cast<<<dim3(4096), dim3(256), 0, stream>>>(dec_w2, w2db, 1048576);
    }

    // ---- 1) decoder masked self-attn: x1 = LN(X + attn(X)) ----
    GEMM(1, 1, X, D, Wh[0], DH, nullptr, qb, D, nullptr, 0, 0, 1.f,
         Bn * T, DH, DH, H, H, 0, DH, 0, DH * DH, 0, DH);
    GEMM(1, 1, X, D, Wh[1], DH, nullptr, kb, D, nullptr, 0, 0, 1.f,
         Bn * T, DH, DH, H, H, 0, DH, 0, DH * DH, 0, DH);
    GEMM(1, 1, X, D, Wh[2], DH, nullptr, vb, D, nullptr, 0, 0, 1.f,
         Bn * T, DH, DH, H, H, 0, DH, 0, DH * DH, 0, DH);
    k_transpose<<<dim3(T / 32, DH / 32, Bn * H), dim3(256), 0, stream>>>(vb, tmpB);
    k_attn<1><<<dim3(T / 64, H, Bn), dim3(256), 0, stream>>>(qb, kb, tmpB, vb, T, 0.0625f);
    k_addln<1, 0><<<dim3(Bn * T), dim3(256), 0, stream>>>(X, vb, ln[0], ln[1], nullptr, x1b);

    // ---- 2) encoder self-attn: c1 = LN(ctx + attn(ctx)) ----
    GEMM(1, 1, ctx, D, Wh[6], DH, nullptr, qb, D, nullptr, 0, 0, 1.f,
         Bn * T, DH, DH, H, H, 0, DH, 0, DH * DH, 0, DH);
    GEMM(1, 1, ctx, D, Wh[7], DH, nullptr, kb, D, nullptr, 0, 0, 1.f,
         Bn * T, DH, DH, H, H, 0, DH, 0, DH * DH, 0, DH);
    GEMM(1, 1, ctx, D, Wh[8], DH, nullptr, vb, D, nullptr, 0, 0, 1.f,
         Bn * T, DH, DH, H, H, 0, DH, 0, DH * DH, 0, DH);
    k_transpose<<<dim3(T / 32, DH / 32, Bn * H), dim3(256), 0, stream>>>(vb, tmpB);
    k_attn<0><<<dim3(T / 64, H, Bn), dim3(256), 0, stream>>>(qb, kb, tmpB, vb, T, 0.0625f);
    k_addln<1, 0><<<dim3(Bn * T), dim3(256), 0, stream>>>(ctx, vb, ln[6], ln[7], nullptr, t2b);

    // ---- 3) encoder FFN (k-chunked): c = LN(c1 + ffn(c1)) -> outC ----
    for (int c = 0; c < 4; c++) {
        if (wcast) {
            GEMM(0, 0, t2b, D, w1eb + (long)c * 1024 * 1024, 1024, nullptr, hb, 1024,
                 enc_b1 + c * 1024, 1, 0, 1.f, Bn * T, 1024, 1024, 1, 1, 0, 0, 0, 0, 0, 0);
            GEMM(0, 0, hb, 1024, w2eb + c * 1024, 4096, tmpF, nullptr, 1024,
                 c == 0 ? enc_b2 : nullptr, 0, c > 0, 1.f,
                 Bn * T, 1024, 1024, 1, 1, 0, 0, 0, 0, 0, 0);
        } else {
            GEMM(0, 1, t2b, D, enc_w1 + (long)c * 1024 * 1024, 1024, nullptr, hb, 1024,
                 enc_b1 + c * 1024, 1, 0, 1.f, Bn * T, 1024, 1024, 1, 1, 0, 0, 0, 0, 0, 0);
            GEMM(0, 1, hb, 1024, enc_w2 + c * 1024, 4096, tmpF, nullptr, 1024,
                 c == 0 ? enc_b2 : nullptr, 0, c > 0, 1.f,
                 Bn * T, 1024, 1024, 1, 1, 0, 0, 0, 0, 0, 0);
        }
    }
    k_addln<0, 1><<<dim3(Bn * T), dim3(256), 0, stream>>>(t2b, tmpF, ln[8], ln[9], outC, nullptr);

    // ---- 4) cross attention (no softmax): o = q (K^T V)^T / 16 ----
    GEMM(0, 1, x1b, D, Wh[3], DH, nullptr, qb, D, nullptr, 0, 0, 1.f,
         Bn * T, DH, DH, H, H, 0, DH, 0, DH * DH, 0, DH);
    GEMM(1, 1, outC, D, Wh[4], DH, nullptr, kb, D, nullptr, 0, 0, 1.f,
         Bn * T, DH, DH, H, H, 0, DH, 0, DH * DH, 0, DH);
    k_transpose<<<dim3(T / 32, DH / 32, Bn * H), dim3(256), 0, stream>>>(kb, Kt);
    GEMM(1, 1, outC, D, Wh[5], DH, nullptr, kb, D, nullptr, 0, 0, 1.f,
         Bn * T, DH, DH, H, H, 0, DH, 0, DH * DH, 0, DH);
    k_transpose<<<dim3(T / 32, DH / 32, Bn * H), dim3(256), 0, stream>>>(kb, Vt);
    // Nm[f][e] = sum_t V[t][f] K[t][e]  per (b,h)
    GEMM(0, 0, Vt, T, Kt, T, nullptr, Nm, DH, nullptr, 0, 0, 1.f,
         DH, DH, T, Bn * H, Bn * H, 0, (long)DH * T, 0, (long)DH * T, 0, DH * DH);
    // o[t][f] = (1/16) sum_e q[t][e] Nm[f][e]  per (b,h)
    GEMM(0, 0, qb, D, Nm, DH, nullptr, tmpB, D, nullptr, 0, 0, 0.0625f,
         T, DH, DH, Bn * H, H, (long)T * D, DH, (long)H * DH * DH, DH * DH,
         (long)T * D, DH);
    k_addln<0, 0><<<dim3(Bn * T), dim3(256), 0, stream>>>(x1b, tmpB, ln[2], ln[3], nullptr, t2b);

    // ---- 5) decoder FFN (k-chunked): out = LN(x2 + ffn(x2)) -> outY ----
    for (int c = 0; c < 4; c++) {
        if (wcast) {
            GEMM(0, 0, t2b, D, w1db + (long)c * 1024 * 1024, 1024, nullptr, hb, 1024,
                 dec_b1 + c * 1024, 1, 0, 1.f, Bn * T, 1024, 1024, 1, 1, 0, 0, 0, 0, 0, 0);
            GEMM(0, 0, hb, 1024, w2db + c * 1024, 4096, tmpF, nullptr, 1024,
                 c == 0 ? dec_b2 : nullptr, 0, c > 0, 1.f,
                 Bn * T, 1024, 1024, 1, 1, 0, 0, 0, 0, 0, 0);
        } else {
            GEMM(0, 1, t2b, D, dec_w1 + (long)c * 1024 * 1024, 1024, nullptr, hb, 1024,
                 dec_b1 + c * 1024, 1, 0, 1.f, Bn * T, 1024, 1024, 1, 1, 0, 0, 0, 0, 0, 0);
            GEMM(0, 1, hb, 1024, dec_w2 + c * 1024, 4096, tmpF, nullptr, 1024,
                 c == 0 ? dec_b2 : nullptr, 0, c > 0, 1.f,
                 Bn * T, 1024, 1024, 1, 1, 0, 0, 0, 0, 0, 0);
        }
    }
    k_addln<0, 1><<<dim3(Bn * T), dim3(256), 0, stream>>>(t2b, tmpF, ln[4], ln[5], outY, nullptr);
}

// Round 5
// 1337.590 us; speedup vs baseline: 1.2929x; 1.2929x over previous
//
#include <hip/hip_runtime.h>
#include <hip/hip_bf16.h>

typedef unsigned short u16;
typedef __bf16 bf16x8 __attribute__((ext_vector_type(8)));
typedef unsigned short u16x8 __attribute__((ext_vector_type(8)));
typedef unsigned short u16x4 __attribute__((ext_vector_type(4)));
typedef float f32x4 __attribute__((ext_vector_type(4)));

#define DI static __device__ __forceinline__

DI u16 f2bf(float f) {
    unsigned u = __builtin_bit_cast(unsigned, f);
    u += 0x7FFFu + ((u >> 16) & 1u);   // round-to-nearest-even
    return (u16)(u >> 16);
}
DI float bf2f(u16 u) {
    unsigned x = ((unsigned)u) << 16;
    return __builtin_bit_cast(float, x);
}
DI u16x8 ld8_f32(const float* __restrict__ p) {
    const float4 a = *(const float4*)p;
    const float4 b = *(const float4*)(p + 4);
    u16x8 r = { f2bf(a.x), f2bf(a.y), f2bf(a.z), f2bf(a.w),
                f2bf(b.x), f2bf(b.y), f2bf(b.z), f2bf(b.w) };
    return r;
}
DI f32x4 mfma16(u16x8 a, u16x8 b, f32x4 c) {
    return __builtin_amdgcn_mfma_f32_16x16x32_bf16(
        __builtin_bit_cast(bf16x8, a), __builtin_bit_cast(bf16x8, b), c, 0, 0, 0);
}

// ---------------------------------------------------------------- cast ----
__global__ void __launch_bounds__(256) k_cast(const float* __restrict__ in,
                                              u16* __restrict__ out, long n4) {
    long i = (long)blockIdx.x * 256 + threadIdx.x;
    if (i >= n4) return;
    const float4 v = *(const float4*)(in + i * 4);
    u16x4 o = { f2bf(v.x), f2bf(v.y), f2bf(v.z), f2bf(v.w) };
    *(u16x4*)(out + i * 4) = o;
}

// ---------------------------------------------------------------- GEMM ----
// C[M,N] = alpha*A[M,K]*B[N,K]^T (+bias[n]) (+C-accum) (+relu).
// A/B may be fp32 (converted during LDS staging) or bf16. fp32 accumulate.
// 128x128 tile, BK=64, 4 waves (2x2), wave = 64x64 = 4x4 frags of 16x16x32.
template <int AF32, int BF32>
__global__ void __launch_bounds__(256) k_gemm_bt(
    const void* __restrict__ Ap, long lda,
    const void* __restrict__ Bp, long ldb,
    float* __restrict__ Cf, u16* __restrict__ Cb, long ldc,
    const float* __restrict__ bias, int relu, int accum, float alpha, int K,
    int Hdiv, long sAb, long sAh, long sBb, long sBh, long sCb, long sCh)
{
    __shared__ __align__(16) u16 As[128 * 72];
    __shared__ __align__(16) u16 Bs[128 * 72];
    const int tid  = threadIdx.x;
    const int lane = tid & 63, wave = tid >> 6;
    const int r16  = lane & 15, quad = lane >> 4;
    const int wr   = (wave >> 1) * 64, wc = (wave & 1) * 64;
    const int zb = blockIdx.z / Hdiv, zh = blockIdx.z % Hdiv;
    const long aoff = (long)zb * sAb + (long)zh * sAh + (long)blockIdx.x * 128 * lda;
    const long boff = (long)zb * sBb + (long)zh * sBh + (long)blockIdx.y * 128 * ldb;
    const u16*   A16 = (const u16*)Ap + aoff;
    const float* A32 = (const float*)Ap + aoff;
    const u16*   B16 = (const u16*)Bp + boff;
    const float* B32 = (const float*)Bp + boff;
    const long coff = (long)zb * sCb + (long)zh * sCh +
                      (long)blockIdx.x * 128 * ldc + (long)blockIdx.y * 128;

    f32x4 acc[4][4];
#pragma unroll
    for (int i = 0; i < 4; i++)
#pragma unroll
        for (int j = 0; j < 4; j++) acc[i][j] = f32x4{0.f, 0.f, 0.f, 0.f};

    const int st_row = tid >> 3;          // 0..31, +32*r
    const int st_col = (tid & 7) * 8;     // 0..56

    for (int k0 = 0; k0 < K; k0 += 64) {
#pragma unroll
        for (int r = 0; r < 4; r++) {
            const int row = st_row + 32 * r;
            if constexpr (AF32)
                *(u16x8*)(As + row * 72 + st_col) = ld8_f32(A32 + (long)row * lda + k0 + st_col);
            else
                *(uint4*)(As + row * 72 + st_col) = *(const uint4*)(A16 + (long)row * lda + k0 + st_col);
            if constexpr (BF32)
                *(u16x8*)(Bs + row * 72 + st_col) = ld8_f32(B32 + (long)row * ldb + k0 + st_col);
            else
                *(uint4*)(Bs + row * 72 + st_col) = *(const uint4*)(B16 + (long)row * ldb + k0 + st_col);
        }
        __syncthreads();
#pragma unroll
        for (int kk = 0; kk < 64; kk += 32) {
            u16x8 af[4], bfr[4];
#pragma unroll
            for (int i = 0; i < 4; i++)
                af[i] = *(const u16x8*)(As + (wr + i * 16 + r16) * 72 + kk + 8 * quad);
#pragma unroll
            for (int j = 0; j < 4; j++)
                bfr[j] = *(const u16x8*)(Bs + (wc + j * 16 + r16) * 72 + kk + 8 * quad);
#pragma unroll
            for (int i = 0; i < 4; i++)
#pragma unroll
                for (int j = 0; j < 4; j++)
                    acc[i][j] = mfma16(af[i], bfr[j], acc[i][j]);
        }
        __syncthreads();
    }

#pragma unroll
    for (int i = 0; i < 4; i++) {
#pragma unroll
        for (int j = 0; j < 4; j++) {
            const int gcol = wc + j * 16 + r16;
            const float bv = bias ? bias[blockIdx.y * 128 + gcol] : 0.f;
#pragma unroll
            for (int r = 0; r < 4; r++) {
                const long o = coff + (long)(wr + i * 16 + quad * 4 + r) * ldc + gcol;
                float v = acc[i][j][r] * alpha + bv;
                if (accum) v += Cf[o];
                if (relu) v = fmaxf(v, 0.f);
                if (Cf) Cf[o] = v;
                if (Cb) Cb[o] = f2bf(v);
            }
        }
    }
}

// ----------------------------------------------------- fused attention ----
// grid (T/64, H, B), 256 thr = 4 waves; wave owns 16 q-rows, DH=256.
// K tile [32 kv][256 d] (stride 264); V^T tile [256 d][32 kv] (stride 40,
// from globally pre-transposed Vt) so the PV B-fragment is one ds_read_b128.
// DIRECT global->LDS staging (R2 structure: proven no-spill, VGPR 132).
// R3/R4 lesson: reg-staged lambdas with uint4 arrays live across barriers
// get demoted to scratch (~1GB WRITE_SIZE) regardless of launch_bounds.
template <int MASKED>
__global__ void __launch_bounds__(256) k_attn(
    const u16* __restrict__ Q, const u16* __restrict__ Kg, const u16* __restrict__ Vt,
    u16* __restrict__ O, int T, float scale)
{
    const int D = 1024;
    __shared__ __align__(16) u16 Ks[32 * 264];
    __shared__ __align__(16) u16 VsT[256 * 40];
    __shared__ __align__(16) u16 Ps[4][16 * 40];
    const int tid = threadIdx.x, lane = tid & 63, wave = tid >> 6;
    const int r16 = lane & 15, quad = lane >> 4;
    const long base   = ((long)blockIdx.z * T) * D + blockIdx.y * 256;
    const long vtbase = ((long)(blockIdx.z * 4 + blockIdx.y) * 256) * 2048;
    const int qr0 = blockIdx.x * 64 + wave * 16;

    u16x8 qf[8];
#pragma unroll
    for (int ks = 0; ks < 8; ks++)
        qf[ks] = *(const u16x8*)(Q + base + (long)(qr0 + r16) * D + ks * 32 + 8 * quad);

    f32x4 oacc[16];
#pragma unroll
    for (int nt = 0; nt < 16; nt++) oacc[nt] = f32x4{0.f, 0.f, 0.f, 0.f};
    float mrun[4] = {-1e30f, -1e30f, -1e30f, -1e30f};
    float lrun[4] = {0.f, 0.f, 0.f, 0.f};

    // K staging map: rows 32 x cols 256
    const int krow = tid >> 5, kcol = (tid & 31) * 8;   // +8*r rows
    // V^T staging map: rows 256 (d) x cols 32 (kv)
    const int vrow = tid >> 2, vcol = (tid & 3) * 8;    // +64*r rows
    const int nkb = MASKED ? (blockIdx.x * 2 + 2) : (T / 32);

    for (int kb = 0; kb < nkb; kb++) {
        // ---- stage K tile + V^T tile directly into LDS ----
#pragma unroll
        for (int r = 0; r < 4; r++)
            *(uint4*)(Ks + (krow + 8 * r) * 264 + kcol) =
                *(const uint4*)(Kg + base + (long)(kb * 32 + krow + 8 * r) * D + kcol);
#pragma unroll
        for (int r = 0; r < 4; r++)
            *(uint4*)(VsT + (vrow + 64 * r) * 40 + vcol) =
                *(const uint4*)(Vt + vtbase + (long)(vrow + 64 * r) * 2048 + kb * 32 + vcol);
        __syncthreads();

        // ---- S = Q K^T (two 16-key halves) ----
        f32x4 s0 = f32x4{0.f,0.f,0.f,0.f}, s1 = f32x4{0.f,0.f,0.f,0.f};
#pragma unroll
        for (int ks = 0; ks < 8; ks++) {
            s0 = mfma16(qf[ks], *(const u16x8*)(Ks + (r16)      * 264 + ks * 32 + 8 * quad), s0);
            s1 = mfma16(qf[ks], *(const u16x8*)(Ks + (16 + r16) * 264 + ks * 32 + 8 * quad), s1);
        }

        // ---- online softmax (16-lane groups) ----
        float p[2][4], al[4];
#pragma unroll
        for (int r = 0; r < 4; r++) {
            float a0 = s0[r] * scale, a1 = s1[r] * scale;
            if (MASKED) {
                const int qi = qr0 + quad * 4 + r;
                if (kb * 32 + r16 > qi)      a0 = -1e30f;
                if (kb * 32 + 16 + r16 > qi) a1 = -1e30f;
            }
            float bm = fmaxf(a0, a1);
#pragma unroll
            for (int m = 1; m < 16; m <<= 1) bm = fmaxf(bm, __shfl_xor(bm, m));
            const float mn = fmaxf(mrun[r], bm);
            al[r] = __expf(mrun[r] - mn);
            const float p0 = __expf(a0 - mn), p1 = __expf(a1 - mn);
            float rs = p0 + p1;
#pragma unroll
            for (int m = 1; m < 16; m <<= 1) rs += __shfl_xor(rs, m);
            lrun[r] = lrun[r] * al[r] + rs;
            mrun[r] = mn;
            p[0][r] = p0; p[1][r] = p1;
        }

        // ---- P -> bf16 via wave-private LDS (A-fragment layout) ----
        u16* pw = &Ps[wave][0];
#pragma unroll
        for (int r = 0; r < 4; r++) {
            pw[(quad * 4 + r) * 40 + r16]      = f2bf(p[0][r]);
            pw[(quad * 4 + r) * 40 + 16 + r16] = f2bf(p[1][r]);
        }
#pragma unroll
        for (int nt = 0; nt < 16; nt++) {
            oacc[nt][0] *= al[0]; oacc[nt][1] *= al[1];
            oacc[nt][2] *= al[2]; oacc[nt][3] *= al[3];
        }
        const u16x8 pf = *(const u16x8*)(pw + r16 * 40 + 8 * quad);

        // ---- O += P V : B-fragment = one b128 from V^T ----
#pragma unroll
        for (int nt = 0; nt < 16; nt++) {
            const u16x8 vf = *(const u16x8*)(VsT + (nt * 16 + r16) * 40 + 8 * quad);
            oacc[nt] = mfma16(pf, vf, oacc[nt]);
        }

        __syncthreads();                       // all waves done with LDS[kb]
    }

#pragma unroll
    for (int nt = 0; nt < 16; nt++)
#pragma unroll
        for (int r = 0; r < 4; r++)
            O[base + (long)(qr0 + quad * 4 + r) * D + nt * 16 + r16] =
                f2bf(oacc[nt][r] / lrun[r]);
}

// ----------------------------------------------------- add + layernorm ----
template <int XF32, int RF32>
__global__ void __launch_bounds__(256) k_addln(
    const void* __restrict__ Xp, const void* __restrict__ Rp,
    const float* __restrict__ G, const float* __restrict__ Bv,
    float* __restrict__ Yf, u16* __restrict__ Yb)
{
    const int tid = threadIdx.x;
    const long off = (long)blockIdx.x * 1024 + tid * 4;
    float v[4];
    if constexpr (XF32) {
        const float4 a = *(const float4*)((const float*)Xp + off);
        v[0] = a.x; v[1] = a.y; v[2] = a.z; v[3] = a.w;
    } else {
        const u16x4 a = *(const u16x4*)((const u16*)Xp + off);
        v[0] = bf2f(a[0]); v[1] = bf2f(a[1]); v[2] = bf2f(a[2]); v[3] = bf2f(a[3]);
    }
    if constexpr (RF32) {
        const float4 b = *(const float4*)((const float*)Rp + off);
        v[0] += b.x; v[1] += b.y; v[2] += b.z; v[3] += b.w;
    } else {
        const u16x4 b = *(const u16x4*)((const u16*)Rp + off);
        v[0] += bf2f(b[0]); v[1] += bf2f(b[1]); v[2] += bf2f(b[2]); v[3] += bf2f(b[3]);
    }
    float s1 = v[0] + v[1] + v[2] + v[3];
    float s2 = v[0]*v[0] + v[1]*v[1] + v[2]*v[2] + v[3]*v[3];
#pragma unroll
    for (int m = 1; m < 64; m <<= 1) { s1 += __shfl_xor(s1, m); s2 += __shfl_xor(s2, m); }
    __shared__ float red[8];
    if ((tid & 63) == 0) { red[(tid >> 6) * 2] = s1; red[(tid >> 6) * 2 + 1] = s2; }
    __syncthreads();
    s1 = red[0] + red[2] + red[4] + red[6];
    s2 = red[1] + red[3] + red[5] + red[7];
    const float mean = s1 * (1.f / 1024.f);
    const float rstd = rsqrtf(s2 * (1.f / 1024.f) - mean * mean + 1e-5f);
    const float4 g  = *(const float4*)(G + tid * 4);
    const float4 be = *(const float4*)(Bv + tid * 4);
    const float o0 = (v[0] - mean) * rstd * g.x + be.x;
    const float o1 = (v[1] - mean) * rstd * g.y + be.y;
    const float o2 = (v[2] - mean) * rstd * g.z + be.z;
    const float o3 = (v[3] - mean) * rstd * g.w + be.w;
    if (Yf) { float4 of = {o0, o1, o2, o3}; *(float4*)(Yf + off) = of; }
    if (Yb) { u16x4 ob = {f2bf(o0), f2bf(o1), f2bf(o2), f2bf(o3)}; *(u16x4*)(Yb + off) = ob; }
}

// -------------------------------------------- per-(b,h) head transpose ----
// X[(b*2048+t)*1024 + h*256 + e] -> Y[(bh*256 + e)*2048 + t]
__global__ void __launch_bounds__(256) k_transpose(const u16* __restrict__ Xin,
                                                   u16* __restrict__ Y)
{
    __shared__ u16 tile[32][33];
    const int tx = threadIdx.x & 31, ty = threadIdx.x >> 5;
    const int t0 = blockIdx.x * 32, e0 = blockIdx.y * 32, bh = blockIdx.z;
    const int b = bh >> 2, h = bh & 3;
#pragma unroll
    for (int i = 0; i < 4; i++)
        tile[ty + 8 * i][tx] =
            Xin[((long)(b * 2048 + t0 + ty + 8 * i)) * 1024 + h * 256 + e0 + tx];
    __syncthreads();
#pragma unroll
    for (int i = 0; i < 4; i++)
        Y[((long)bh * 256 + e0 + ty + 8 * i) * 2048 + t0 + tx] = tile[tx][ty + 8 * i];
}

// ------------------------------------------------------------- driver ----
#define GEMM(AF, BF, Aptr, lda, Bptr, ldb, pCf, pCb, ldc, bias, relu, accum, alpha, \
             M, N, K, Z, Hdiv, sAb, sAh, sBb, sBh, sCb, sCh)                        \
    k_gemm_bt<AF, BF><<<dim3((M) / 128, (N) / 128, (Z)), dim3(256), 0, stream>>>(   \
        (const void*)(Aptr), (lda), (const void*)(Bptr), (ldb), (pCf), (pCb),       \
        (ldc), (bias), (relu), (accum), (alpha), (K), (Hdiv),                       \
        (long)(sAb), (long)(sAh), (long)(sBb), (long)(sBh), (long)(sCb), (long)(sCh))

extern "C" void kernel_launch(void* const* d_in, const int* in_sizes, int n_in,
                              void* d_out, int out_size, void* d_ws, size_t ws_size,
                              hipStream_t stream)
{
    const int Bn = 4, T = 2048, D = 1024, H = 4, DH = 256;
    const long BTD = (long)Bn * T * D;           // 8388608 elems
    const long MB = 1024 * 1024;

    const float* ctx = (const float*)d_in[0];
    const float* X   = (const float*)d_in[1];
    const float* Wh[9]; for (int i = 0; i < 9; i++) Wh[i] = (const float*)d_in[2 + i];
    const float* dec_w1 = (const float*)d_in[11]; const float* dec_b1 = (const float*)d_in[12];
    const float* dec_w2 = (const float*)d_in[13]; const float* dec_b2 = (const float*)d_in[14];
    const float* enc_w1 = (const float*)d_in[15]; const float* enc_b1 = (const float*)d_in[16];
    const float* enc_w2 = (const float*)d_in[17]; const float* enc_b2 = (const float*)d_in[18];
    const float* ln[10]; for (int i = 0; i < 10; i++) ln[i] = (const float*)d_in[19 + i];
    (void)in_sizes; (void)n_in; (void)out_size;

    float* outC = (float*)d_out;        // c  [B,T,D] fp32
    float* outY = (float*)d_out + BTD;  // out[B,T,D] fp32

    // ---- workspace pool (98.3 MB core) ----
    char* w = (char*)d_ws;
    u16*   qb   = (u16*)(w);                 // 16 MB
    u16*   kb   = (u16*)(w + 16 * MB);       // 16 MB
    u16*   vb   = (u16*)(w + 32 * MB);       // 16 MB (V proj; then attn out)
    u16*   tmpB = (u16*)(w + 48 * MB);       // 16 MB (V^T for attn; cross out)
    u16*   hb   = (u16*)(w);                 // 16 MB (FFN hidden chunk)
    float* tmpF = (float*)(w + 32 * MB);     // 32 MB (FFN fp32 accum)
    u16*   Vt   = (u16*)(w + 32 * MB);       // 16 MB (cross V^T)
    u16*   Kt   = (u16*)(w + 48 * MB);       // 16 MB (cross K^T)
    u16*   Nm   = (u16*)(w + 64 * MB);       //  2 MB
    u16*   x1b  = (u16*)(w + 66 * MB);       // 16 MB
    u16*   t2b  = (u16*)(w + 82 * MB);       // 16 MB (c1, then x2)
    const bool wcast = ws_size >= 140 * (size_t)MB;
    u16* w1eb = (u16*)(w + 98 * MB);  u16* w2eb = (u16*)(w + 106 * MB);
    u16* w1db = (u16*)(w + 114 * MB); u16* w2db = (u16*)(w + 122 * MB);

    if (wcast) {
        k_cast<<<dim3(4096), dim3(256), 0, stream>>>(enc_w1, w1eb, 1048576);
        k_cast<<<dim3(4096), dim3(256), 0, stream>>>(enc_w2, w2eb, 1048576);
        k_cast<<<dim3(4096), dim3(256), 0, stream>>>(dec_w1, w1db, 1048576);
        k_cast<<<dim3(4096), dim3(256), 0, stream>>>(dec_w2, w2db, 1048576);
    }

    // ---- 1) decoder masked self-attn: x1 = LN(X + attn(X)) ----
    GEMM(1, 1, X, D, Wh[0], DH, nullptr, qb, D, nullptr, 0, 0, 1.f,
         Bn * T, DH, DH, H, H, 0, DH, 0, DH * DH, 0, DH);
    GEMM(1, 1, X, D, Wh[1], DH, nullptr, kb, D, nullptr, 0, 0, 1.f,
         Bn * T, DH, DH, H, H, 0, DH, 0, DH * DH, 0, DH);
    GEMM(1, 1, X, D, Wh[2], DH, nullptr, vb, D, nullptr, 0, 0, 1.f,
         Bn * T, DH, DH, H, H, 0, DH, 0, DH * DH, 0, DH);
    k_transpose<<<dim3(T / 32, DH / 32, Bn * H), dim3(256), 0, stream>>>(vb, tmpB);
    k_attn<1><<<dim3(T / 64, H, Bn), dim3(256), 0, stream>>>(qb, kb, tmpB, vb, T, 0.0625f);
    k_addln<1, 0><<<dim3(Bn * T), dim3(256), 0, stream>>>(X, vb, ln[0], ln[1], nullptr, x1b);

    // ---- 2) encoder self-attn: c1 = LN(ctx + attn(ctx)) ----
    GEMM(1, 1, ctx, D, Wh[6], DH, nullptr, qb, D, nullptr, 0, 0, 1.f,
         Bn * T, DH, DH, H, H, 0, DH, 0, DH * DH, 0, DH);
    GEMM(1, 1, ctx, D, Wh[7], DH, nullptr, kb, D, nullptr, 0, 0, 1.f,
         Bn * T, DH, DH, H, H, 0, DH, 0, DH * DH, 0, DH);
    GEMM(1, 1, ctx, D, Wh[8], DH, nullptr, vb, D, nullptr, 0, 0, 1.f,
         Bn * T, DH, DH, H, H, 0, DH, 0, DH * DH, 0, DH);
    k_transpose<<<dim3(T / 32, DH / 32, Bn * H), dim3(256), 0, stream>>>(vb, tmpB);
    k_attn<0><<<dim3(T / 64, H, Bn), dim3(256), 0, stream>>>(qb, kb, tmpB, vb, T, 0.0625f);
    k_addln<1, 0><<<dim3(Bn * T), dim3(256), 0, stream>>>(ctx, vb, ln[6], ln[7], nullptr, t2b);

    // ---- 3) encoder FFN (k-chunked): c = LN(c1 + ffn(c1)) -> outC ----
    for (int c = 0; c < 4; c++) {
        if (wcast) {
            GEMM(0, 0, t2b, D, w1eb + (long)c * 1024 * 1024, 1024, nullptr, hb, 1024,
                 enc_b1 + c * 1024, 1, 0, 1.f, Bn * T, 1024, 1024, 1, 1, 0, 0, 0, 0, 0, 0);
            GEMM(0, 0, hb, 1024, w2eb + c * 1024, 4096, tmpF, nullptr, 1024,
                 c == 0 ? enc_b2 : nullptr, 0, c > 0, 1.f,
                 Bn * T, 1024, 1024, 1, 1, 0, 0, 0, 0, 0, 0);
        } else {
            GEMM(0, 1, t2b, D, enc_w1 + (long)c * 1024 * 1024, 1024, nullptr, hb, 1024,
                 enc_b1 + c * 1024, 1, 0, 1.f, Bn * T, 1024, 1024, 1, 1, 0, 0, 0, 0, 0, 0);
            GEMM(0, 1, hb, 1024, enc_w2 + c * 1024, 4096, tmpF, nullptr, 1024,
                 c == 0 ? enc_b2 : nullptr, 0, c > 0, 1.f,
                 Bn * T, 1024, 1024, 1, 1, 0, 0, 0, 0, 0, 0);
        }
    }
    k_addln<0, 1><<<dim3(Bn * T), dim3(256), 0, stream>>>(t2b, tmpF, ln[8], ln[9], outC, nullptr);

    // ---- 4) cross attention (no softmax): o = q (K^T V)^T / 16 ----
    GEMM(0, 1, x1b, D, Wh[3], DH, nullptr, qb, D, nullptr, 0, 0, 1.f,
         Bn * T, DH, DH, H, H, 0, DH, 0, DH * DH, 0, DH);
    GEMM(1, 1, outC, D, Wh[4], DH, nullptr, kb, D, nullptr, 0, 0, 1.f,
         Bn * T, DH, DH, H, H, 0, DH, 0, DH * DH, 0, DH);
    k_transpose<<<dim3(T / 32, DH / 32, Bn * H), dim3(256), 0, stream>>>(kb, Kt);
    GEMM(1, 1, outC, D, Wh[5], DH, nullptr, kb, D, nullptr, 0, 0, 1.f,
         Bn * T, DH, DH, H, H, 0, DH, 0, DH * DH, 0, DH);
    k_transpose<<<dim3(T / 32, DH / 32, Bn * H), dim3(256), 0, stream>>>(kb, Vt);
    // Nm[f][e] = sum_t V[t][f] K[t][e]  per (b,h)
    GEMM(0, 0, Vt, T, Kt, T, nullptr, Nm, DH, nullptr, 0, 0, 1.f,
         DH, DH, T, Bn * H, Bn * H, 0, (long)DH * T, 0, (long)DH * T, 0, DH * DH);
    // o[t][f] = (1/16) sum_e q[t][e] Nm[f][e]  per (b,h)
    GEMM(0, 0, qb, D, Nm, DH, nullptr, tmpB, D, nullptr, 0, 0, 0.0625f,
         T, DH, DH, Bn * H, H, (long)T * D, DH, (long)H * DH * DH, DH * DH,
         (long)T * D, DH);
    k_addln<0, 0><<<dim3(Bn * T), dim3(256), 0, stream>>>(x1b, tmpB, ln[2], ln[3], nullptr, t2b);

    // ---- 5) decoder FFN (k-chunked): out = LN(x2 + ffn(x2)) -> outY ----
    for (int c = 0; c < 4; c++) {
        if (wcast) {
            GEMM(0, 0, t2b, D, w1db + (long)c * 1024 * 1024, 1024, nullptr, hb, 1024,
                 dec_b1 + c * 1024, 1, 0, 1.f, Bn * T, 1024, 1024, 1, 1, 0, 0, 0, 0, 0, 0);
            GEMM(0, 0, hb, 1024, w2db + c * 1024, 4096, tmpF, nullptr, 1024,
                 c == 0 ? dec_b2 : nullptr, 0, c > 0, 1.f,
                 Bn * T, 1024, 1024, 1, 1, 0, 0, 0, 0, 0, 0);
        } else {
            GEMM(0, 1, t2b, D, dec_w1 + (long)c * 1024 * 1024, 1024, nullptr, hb, 1024,
                 dec_b1 + c * 1024, 1, 0, 1.f, Bn * T, 1024, 1024, 1, 1, 0, 0, 0, 0, 0, 0);
            GEMM(0, 1, hb, 1024, dec_w2 + c * 1024, 4096, tmpF, nullptr, 1024,
                 c == 0 ? dec_b2 : nullptr, 0, c > 0, 1.f,
                 Bn * T, 1024, 1024, 1, 1, 0, 0, 0, 0, 0, 0);
        }
    }
    k_addln<0, 1><<<dim3(Bn * T), dim3(256), 0, stream>>>(t2b, tmpF, ln[4], ln[5], outY, nullptr);
}

// Round 6
// 1177.528 us; speedup vs baseline: 1.4686x; 1.1359x over previous
//
#include <hip/hip_runtime.h>
#include <hip/hip_bf16.h>

typedef unsigned short u16;
typedef __bf16 bf16x8 __attribute__((ext_vector_type(8)));
typedef unsigned short u16x8 __attribute__((ext_vector_type(8)));
typedef unsigned short u16x4 __attribute__((ext_vector_type(4)));
typedef float f32x4 __attribute__((ext_vector_type(4)));

#define DI static __device__ __forceinline__

DI u16 f2bf(float f) {
    unsigned u = __builtin_bit_cast(unsigned, f);
    u += 0x7FFFu + ((u >> 16) & 1u);   // round-to-nearest-even
    return (u16)(u >> 16);
}
DI float bf2f(u16 u) {
    unsigned x = ((unsigned)u) << 16;
    return __builtin_bit_cast(float, x);
}
DI u16x8 ld8_f32(const float* __restrict__ p) {
    const float4 a = *(const float4*)p;
    const float4 b = *(const float4*)(p + 4);
    u16x8 r = { f2bf(a.x), f2bf(a.y), f2bf(a.z), f2bf(a.w),
                f2bf(b.x), f2bf(b.y), f2bf(b.z), f2bf(b.w) };
    return r;
}
DI f32x4 mfma16(u16x8 a, u16x8 b, f32x4 c) {
    return __builtin_amdgcn_mfma_f32_16x16x32_bf16(
        __builtin_bit_cast(bf16x8, a), __builtin_bit_cast(bf16x8, b), c, 0, 0, 0);
}

// ---------------------------------------------------------------- cast ----
__global__ void __launch_bounds__(256) k_cast(const float* __restrict__ in,
                                              u16* __restrict__ out, long n4) {
    long i = (long)blockIdx.x * 256 + threadIdx.x;
    if (i >= n4) return;
    const float4 v = *(const float4*)(in + i * 4);
    u16x4 o = { f2bf(v.x), f2bf(v.y), f2bf(v.z), f2bf(v.w) };
    *(u16x4*)(out + i * 4) = o;
}

// ---------------------------------------------------------------- GEMM ----
// C[M,N] = alpha*A[M,K]*B[N,K]^T (+bias[n]) (+C-accum) (+relu).
// A/B may be fp32 (converted during LDS staging) or bf16. fp32 accumulate.
// 128x128 tile, BK=64, 4 waves (2x2), wave = 64x64 = 4x4 frags of 16x16x32.
template <int AF32, int BF32>
__global__ void __launch_bounds__(256) k_gemm_bt(
    const void* __restrict__ Ap, long lda,
    const void* __restrict__ Bp, long ldb,
    float* __restrict__ Cf, u16* __restrict__ Cb, long ldc,
    const float* __restrict__ bias, int relu, int accum, float alpha, int K,
    int Hdiv, long sAb, long sAh, long sBb, long sBh, long sCb, long sCh)
{
    __shared__ __align__(16) u16 As[128 * 72];
    __shared__ __align__(16) u16 Bs[128 * 72];
    const int tid  = threadIdx.x;
    const int lane = tid & 63, wave = tid >> 6;
    const int r16  = lane & 15, quad = lane >> 4;
    const int wr   = (wave >> 1) * 64, wc = (wave & 1) * 64;
    const int zb = blockIdx.z / Hdiv, zh = blockIdx.z % Hdiv;
    const long aoff = (long)zb * sAb + (long)zh * sAh + (long)blockIdx.x * 128 * lda;
    const long boff = (long)zb * sBb + (long)zh * sBh + (long)blockIdx.y * 128 * ldb;
    const u16*   A16 = (const u16*)Ap + aoff;
    const float* A32 = (const float*)Ap + aoff;
    const u16*   B16 = (const u16*)Bp + boff;
    const float* B32 = (const float*)Bp + boff;
    const long coff = (long)zb * sCb + (long)zh * sCh +
                      (long)blockIdx.x * 128 * ldc + (long)blockIdx.y * 128;

    f32x4 acc[4][4];
#pragma unroll
    for (int i = 0; i < 4; i++)
#pragma unroll
        for (int j = 0; j < 4; j++) acc[i][j] = f32x4{0.f, 0.f, 0.f, 0.f};

    const int st_row = tid >> 3;          // 0..31, +32*r
    const int st_col = (tid & 7) * 8;     // 0..56

    for (int k0 = 0; k0 < K; k0 += 64) {
#pragma unroll
        for (int r = 0; r < 4; r++) {
            const int row = st_row + 32 * r;
            if constexpr (AF32)
                *(u16x8*)(As + row * 72 + st_col) = ld8_f32(A32 + (long)row * lda + k0 + st_col);
            else
                *(uint4*)(As + row * 72 + st_col) = *(const uint4*)(A16 + (long)row * lda + k0 + st_col);
            if constexpr (BF32)
                *(u16x8*)(Bs + row * 72 + st_col) = ld8_f32(B32 + (long)row * ldb + k0 + st_col);
            else
                *(uint4*)(Bs + row * 72 + st_col) = *(const uint4*)(B16 + (long)row * ldb + k0 + st_col);
        }
        __syncthreads();
#pragma unroll
        for (int kk = 0; kk < 64; kk += 32) {
            u16x8 af[4], bfr[4];
#pragma unroll
            for (int i = 0; i < 4; i++)
                af[i] = *(const u16x8*)(As + (wr + i * 16 + r16) * 72 + kk + 8 * quad);
#pragma unroll
            for (int j = 0; j < 4; j++)
                bfr[j] = *(const u16x8*)(Bs + (wc + j * 16 + r16) * 72 + kk + 8 * quad);
#pragma unroll
            for (int i = 0; i < 4; i++)
#pragma unroll
                for (int j = 0; j < 4; j++)
                    acc[i][j] = mfma16(af[i], bfr[j], acc[i][j]);
        }
        __syncthreads();
    }

#pragma unroll
    for (int i = 0; i < 4; i++) {
#pragma unroll
        for (int j = 0; j < 4; j++) {
            const int gcol = wc + j * 16 + r16;
            const float bv = bias ? bias[blockIdx.y * 128 + gcol] : 0.f;
#pragma unroll
            for (int r = 0; r < 4; r++) {
                const long o = coff + (long)(wr + i * 16 + quad * 4 + r) * ldc + gcol;
                float v = acc[i][j][r] * alpha + bv;
                if (accum) v += Cf[o];
                if (relu) v = fmaxf(v, 0.f);
                if (Cf) Cf[o] = v;
                if (Cb) Cb[o] = f2bf(v);
            }
        }
    }
}

// ----------------------------------------------------- fused attention ----
// grid (T/64, H, B), 256 thr = 4 waves; wave owns 16 q-rows, DH=256.
// KVBLK=64: K tile [64 kv][256 d] (stride 264); V^T tile [256 d][64 kv]
// (stride 72, from globally pre-transposed Vt) -> PV B-frag = ds_read_b128.
// NAMED-register prefetch (no arrays/lambdas -> no address capture -> no
// scratch): issue tile kb+1 loads before compute, ds_write after barrier.
// Defer-max (T13, THR=8): skip O-rescale unless tile max grows > 8.
template <int MASKED>
__global__ void __launch_bounds__(256, 2) k_attn(
    const u16* __restrict__ Q, const u16* __restrict__ Kg, const u16* __restrict__ Vt,
    u16* __restrict__ O, int T, float scale)
{
    const int D = 1024;
    __shared__ __align__(16) u16 Ks[64 * 264];      // 33.8 KB
    __shared__ __align__(16) u16 VsT[256 * 72];     // 36.9 KB
    __shared__ __align__(16) u16 Ps[4][16 * 72];    //  9.2 KB
    const int tid = threadIdx.x, lane = tid & 63, wave = tid >> 6;
    const int r16 = lane & 15, quad = lane >> 4;
    const long base   = ((long)blockIdx.z * T) * D + blockIdx.y * 256;
    const long vtbase = ((long)(blockIdx.z * 4 + blockIdx.y) * 256) * 2048;
    const int qr0 = blockIdx.x * 64 + wave * 16;

    u16x8 qf[8];
#pragma unroll
    for (int ks = 0; ks < 8; ks++)
        qf[ks] = *(const u16x8*)(Q + base + (long)(qr0 + r16) * D + ks * 32 + 8 * quad);

    f32x4 oacc[16];
#pragma unroll
    for (int nt = 0; nt < 16; nt++) oacc[nt] = f32x4{0.f, 0.f, 0.f, 0.f};
    float mrun[4] = {-1e30f, -1e30f, -1e30f, -1e30f};
    float lrun[4] = {0.f, 0.f, 0.f, 0.f};

    // K staging: 64 rows x 256 cols; thread -> row krow+8i, col kcol
    const int krow = tid >> 5, kcol = (tid & 31) * 8;
    // V^T staging: 256 rows x 64 cols; thread -> row vrow+32i, col vcol
    const int vrow = tid >> 3, vcol = (tid & 7) * 8;
    const int nkb = MASKED ? (blockIdx.x + 1) : (T / 64);

    const u16* kg = Kg + base;
    const u16* vg = Vt + vtbase + (long)vrow * 2048 + vcol;

    uint4 kr0, kr1, kr2, kr3, kr4, kr5, kr6, kr7;
    uint4 vr0, vr1, vr2, vr3, vr4, vr5, vr6, vr7;

#define LD_KV(KB)                                                          \
    do {                                                                   \
        const u16* kp_ = kg + ((long)(KB) * 64 + krow) * D + kcol;         \
        kr0 = *(const uint4*)(kp_);                                        \
        kr1 = *(const uint4*)(kp_ + 8 * D);                                \
        kr2 = *(const uint4*)(kp_ + 16 * D);                               \
        kr3 = *(const uint4*)(kp_ + 24 * D);                               \
        kr4 = *(const uint4*)(kp_ + 32 * D);                               \
        kr5 = *(const uint4*)(kp_ + 40 * D);                               \
        kr6 = *(const uint4*)(kp_ + 48 * D);                               \
        kr7 = *(const uint4*)(kp_ + 56 * D);                               \
        const u16* vp_ = vg + (KB) * 64;                                   \
        vr0 = *(const uint4*)(vp_);                                        \
        vr1 = *(const uint4*)(vp_ + 32 * 2048);                            \
        vr2 = *(const uint4*)(vp_ + 64 * 2048);                            \
        vr3 = *(const uint4*)(vp_ + 96 * 2048);                            \
        vr4 = *(const uint4*)(vp_ + 128 * 2048);                           \
        vr5 = *(const uint4*)(vp_ + 160 * 2048);                           \
        vr6 = *(const uint4*)(vp_ + 192 * 2048);                           \
        vr7 = *(const uint4*)(vp_ + 224 * 2048);                           \
    } while (0)

#define ST_KV()                                                            \
    do {                                                                   \
        u16* kq_ = Ks + krow * 264 + kcol;                                 \
        *(uint4*)(kq_)            = kr0;                                   \
        *(uint4*)(kq_ + 8 * 264)  = kr1;                                   \
        *(uint4*)(kq_ + 16 * 264) = kr2;                                   \
        *(uint4*)(kq_ + 24 * 264) = kr3;                                   \
        *(uint4*)(kq_ + 32 * 264) = kr4;                                   \
        *(uint4*)(kq_ + 40 * 264) = kr5;                                   \
        *(uint4*)(kq_ + 48 * 264) = kr6;                                   \
        *(uint4*)(kq_ + 56 * 264) = kr7;                                   \
        u16* vq_ = VsT + vrow * 72 + vcol;                                 \
        *(uint4*)(vq_)            = vr0;                                   \
        *(uint4*)(vq_ + 32 * 72)  = vr1;                                   \
        *(uint4*)(vq_ + 64 * 72)  = vr2;                                   \
        *(uint4*)(vq_ + 96 * 72)  = vr3;                                   \
        *(uint4*)(vq_ + 128 * 72) = vr4;                                   \
        *(uint4*)(vq_ + 160 * 72) = vr5;                                   \
        *(uint4*)(vq_ + 192 * 72) = vr6;                                   \
        *(uint4*)(vq_ + 224 * 72) = vr7;                                   \
    } while (0)

    LD_KV(0);
    ST_KV();
    __syncthreads();

    u16* const pw = &Ps[wave][0];

    for (int kb = 0; kb < nkb; kb++) {
        const bool more = (kb + 1 < nkb);
        if (more) LD_KV(kb + 1);     // global latency hides under compute

        // ---- S = Q K^T : 4 x 16-key fragments ----
        f32x4 s0 = f32x4{0.f,0.f,0.f,0.f}, s1 = f32x4{0.f,0.f,0.f,0.f};
        f32x4 s2 = f32x4{0.f,0.f,0.f,0.f}, s3 = f32x4{0.f,0.f,0.f,0.f};
#pragma unroll
        for (int ks = 0; ks < 8; ks++) {
            const u16x8 a = qf[ks];
            const u16* kp = Ks + r16 * 264 + ks * 32 + 8 * quad;
            s0 = mfma16(a, *(const u16x8*)(kp),            s0);
            s1 = mfma16(a, *(const u16x8*)(kp + 16 * 264), s1);
            s2 = mfma16(a, *(const u16x8*)(kp + 32 * 264), s2);
            s3 = mfma16(a, *(const u16x8*)(kp + 48 * 264), s3);
        }

        // ---- online softmax with defer-max (THR=8) ----
        float al[4];
        bool need = false;
#pragma unroll
        for (int r = 0; r < 4; r++) {
            float a0 = s0[r] * scale, a1 = s1[r] * scale;
            float a2 = s2[r] * scale, a3 = s3[r] * scale;
            if (MASKED) {
                const int qi = qr0 + quad * 4 + r;
                const int kb0 = kb * 64;
                if (kb0 + r16 > qi)      a0 = -1e30f;
                if (kb0 + 16 + r16 > qi) a1 = -1e30f;
                if (kb0 + 32 + r16 > qi) a2 = -1e30f;
                if (kb0 + 48 + r16 > qi) a3 = -1e30f;
            }
            float bm = fmaxf(fmaxf(a0, a1), fmaxf(a2, a3));
#pragma unroll
            for (int m = 1; m < 16; m <<= 1) bm = fmaxf(bm, __shfl_xor(bm, m));
            float alr = 1.f;
            if (bm > mrun[r] + 8.f) {            // rescale only on real growth
                alr = __expf(mrun[r] - bm);
                mrun[r] = bm;
                need = true;
            }
            al[r] = alr;
            const float p0 = __expf(a0 - mrun[r]), p1 = __expf(a1 - mrun[r]);
            const float p2 = __expf(a2 - mrun[r]), p3 = __expf(a3 - mrun[r]);
            float rs = (p0 + p1) + (p2 + p3);
#pragma unroll
            for (int m = 1; m < 16; m <<= 1) rs += __shfl_xor(rs, m);
            lrun[r] = lrun[r] * alr + rs;
            u16* pr = pw + (quad * 4 + r) * 72 + r16;
            pr[0]  = f2bf(p0);
            pr[16] = f2bf(p1);
            pr[32] = f2bf(p2);
            pr[48] = f2bf(p3);
        }
        if (need) {
#pragma unroll
            for (int nt = 0; nt < 16; nt++) {
                oacc[nt][0] *= al[0]; oacc[nt][1] *= al[1];
                oacc[nt][2] *= al[2]; oacc[nt][3] *= al[3];
            }
        }

        // ---- O += P V : A-frags from wave-private Ps, B-frags from V^T ----
        const u16* pp = pw + r16 * 72 + 8 * quad;
        const u16x8 pfA = *(const u16x8*)(pp);
        const u16x8 pfB = *(const u16x8*)(pp + 32);
#pragma unroll
        for (int nt = 0; nt < 16; nt++) {
            const u16* vp = VsT + (nt * 16 + r16) * 72 + 8 * quad;
            oacc[nt] = mfma16(pfA, *(const u16x8*)(vp),      oacc[nt]);
            oacc[nt] = mfma16(pfB, *(const u16x8*)(vp + 32), oacc[nt]);
        }

        __syncthreads();             // all waves done reading LDS[kb]
        if (more) {
            ST_KV();
            __syncthreads();         // LDS[kb+1] visible before next compute
        }
    }
#undef LD_KV
#undef ST_KV

#pragma unroll
    for (int nt = 0; nt < 16; nt++)
#pragma unroll
        for (int r = 0; r < 4; r++)
            O[base + (long)(qr0 + quad * 4 + r) * D + nt * 16 + r16] =
                f2bf(oacc[nt][r] / lrun[r]);
}

// ----------------------------------------------------- add + layernorm ----
template <int XF32, int RF32>
__global__ void __launch_bounds__(256) k_addln(
    const void* __restrict__ Xp, const void* __restrict__ Rp,
    const float* __restrict__ G, const float* __restrict__ Bv,
    float* __restrict__ Yf, u16* __restrict__ Yb)
{
    const int tid = threadIdx.x;
    const long off = (long)blockIdx.x * 1024 + tid * 4;
    float v[4];
    if constexpr (XF32) {
        const float4 a = *(const float4*)((const float*)Xp + off);
        v[0] = a.x; v[1] = a.y; v[2] = a.z; v[3] = a.w;
    } else {
        const u16x4 a = *(const u16x4*)((const u16*)Xp + off);
        v[0] = bf2f(a[0]); v[1] = bf2f(a[1]); v[2] = bf2f(a[2]); v[3] = bf2f(a[3]);
    }
    if constexpr (RF32) {
        const float4 b = *(const float4*)((const float*)Rp + off);
        v[0] += b.x; v[1] += b.y; v[2] += b.z; v[3] += b.w;
    } else {
        const u16x4 b = *(const u16x4*)((const u16*)Rp + off);
        v[0] += bf2f(b[0]); v[1] += bf2f(b[1]); v[2] += bf2f(b[2]); v[3] += bf2f(b[3]);
    }
    float s1 = v[0] + v[1] + v[2] + v[3];
    float s2 = v[0]*v[0] + v[1]*v[1] + v[2]*v[2] + v[3]*v[3];
#pragma unroll
    for (int m = 1; m < 64; m <<= 1) { s1 += __shfl_xor(s1, m); s2 += __shfl_xor(s2, m); }
    __shared__ float red[8];
    if ((tid & 63) == 0) { red[(tid >> 6) * 2] = s1; red[(tid >> 6) * 2 + 1] = s2; }
    __syncthreads();
    s1 = red[0] + red[2] + red[4] + red[6];
    s2 = red[1] + red[3] + red[5] + red[7];
    const float mean = s1 * (1.f / 1024.f);
    const float rstd = rsqrtf(s2 * (1.f / 1024.f) - mean * mean + 1e-5f);
    const float4 g  = *(const float4*)(G + tid * 4);
    const float4 be = *(const float4*)(Bv + tid * 4);
    const float o0 = (v[0] - mean) * rstd * g.x + be.x;
    const float o1 = (v[1] - mean) * rstd * g.y + be.y;
    const float o2 = (v[2] - mean) * rstd * g.z + be.z;
    const float o3 = (v[3] - mean) * rstd * g.w + be.w;
    if (Yf) { float4 of = {o0, o1, o2, o3}; *(float4*)(Yf + off) = of; }
    if (Yb) { u16x4 ob = {f2bf(o0), f2bf(o1), f2bf(o2), f2bf(o3)}; *(u16x4*)(Yb + off) = ob; }
}

// -------------------------------------------- per-(b,h) head transpose ----
// X[(b*2048+t)*1024 + h*256 + e] -> Y[(bh*256 + e)*2048 + t]
__global__ void __launch_bounds__(256) k_transpose(const u16* __restrict__ Xin,
                                                   u16* __restrict__ Y)
{
    __shared__ u16 tile[32][33];
    const int tx = threadIdx.x & 31, ty = threadIdx.x >> 5;
    const int t0 = blockIdx.x * 32, e0 = blockIdx.y * 32, bh = blockIdx.z;
    const int b = bh >> 2, h = bh & 3;
#pragma unroll
    for (int i = 0; i < 4; i++)
        tile[ty + 8 * i][tx] =
            Xin[((long)(b * 2048 + t0 + ty + 8 * i)) * 1024 + h * 256 + e0 + tx];
    __syncthreads();
#pragma unroll
    for (int i = 0; i < 4; i++)
        Y[((long)bh * 256 + e0 + ty + 8 * i) * 2048 + t0 + tx] = tile[tx][ty + 8 * i];
}

// ------------------------------------------------------------- driver ----
#define GEMM(AF, BF, Aptr, lda, Bptr, ldb, pCf, pCb, ldc, bias, relu, accum, alpha, \
             M, N, K, Z, Hdiv, sAb, sAh, sBb, sBh, sCb, sCh)                        \
    k_gemm_bt<AF, BF><<<dim3((M) / 128, (N) / 128, (Z)), dim3(256), 0, stream>>>(   \
        (const void*)(Aptr), (lda), (const void*)(Bptr), (ldb), (pCf), (pCb),       \
        (ldc), (bias), (relu), (accum), (alpha), (K), (Hdiv),                       \
        (long)(sAb), (long)(sAh), (long)(sBb), (long)(sBh), (long)(sCb), (long)(sCh))

extern "C" void kernel_launch(void* const* d_in, const int* in_sizes, int n_in,
                              void* d_out, int out_size, void* d_ws, size_t ws_size,
                              hipStream_t stream)
{
    const int Bn = 4, T = 2048, D = 1024, H = 4, DH = 256;
    const long BTD = (long)Bn * T * D;           // 8388608 elems
    const long MB = 1024 * 1024;

    const float* ctx = (const float*)d_in[0];
    const float* X   = (const float*)d_in[1];
    const float* Wh[9]; for (int i = 0; i < 9; i++) Wh[i] = (const float*)d_in[2 + i];
    const float* dec_w1 = (const float*)d_in[11]; const float* dec_b1 = (const float*)d_in[12];
    const float* dec_w2 = (const float*)d_in[13]; const float* dec_b2 = (const float*)d_in[14];
    const float* enc_w1 = (const float*)d_in[15]; const float* enc_b1 = (const float*)d_in[16];
    const float* enc_w2 = (const float*)d_in[17]; const float* enc_b2 = (const float*)d_in[18];
    const float* ln[10]; for (int i = 0; i < 10; i++) ln[i] = (const float*)d_in[19 + i];
    (void)in_sizes; (void)n_in; (void)out_size;

    float* outC = (float*)d_out;        // c  [B,T,D] fp32
    float* outY = (float*)d_out + BTD;  // out[B,T,D] fp32

    // ---- workspace pool (98.3 MB core) ----
    char* w = (char*)d_ws;
    u16*   qb   = (u16*)(w);                 // 16 MB
    u16*   kb   = (u16*)(w + 16 * MB);       // 16 MB
    u16*   vb   = (u16*)(w + 32 * MB);       // 16 MB (V proj; then attn out)
    u16*   tmpB = (u16*)(w + 48 * MB);       // 16 MB (V^T for attn; cross out)
    u16*   hb   = (u16*)(w);                 // 16 MB (FFN hidden chunk)
    float* tmpF = (float*)(w + 32 * MB);     // 32 MB (FFN fp32 accum)
    u16*   Vt   = (u16*)(w + 32 * MB);       // 16 MB (cross V^T)
    u16*   Kt   = (u16*)(w + 48 * MB);       // 16 MB (cross K^T)
    u16*   Nm   = (u16*)(w + 64 * MB);       //  2 MB
    u16*   x1b  = (u16*)(w + 66 * MB);       // 16 MB
    u16*   t2b  = (u16*)(w + 82 * MB);       // 16 MB (c1, then x2)
    const bool wcast = ws_size >= 140 * (size_t)MB;
    u16* w1eb = (u16*)(w + 98 * MB);  u16* w2eb = (u16*)(w + 106 * MB);
    u16* w1db = (u16*)(w + 114 * MB); u16* w2db = (u16*)(w + 122 * MB);

    if (wcast) {
        k_cast<<<dim3(4096), dim3(256), 0, stream>>>(enc_w1, w1eb, 1048576);
        k_cast<<<dim3(4096), dim3(256), 0, stream>>>(enc_w2, w2eb, 1048576);
        k_cast<<<dim3(4096), dim3(256), 0, stream>>>(dec_w1, w1db, 1048576);
        k_cast<<<dim3(4096), dim3(256), 0, stream>>>(dec_w2, w2db, 1048576);
    }

    // ---- 1) decoder masked self-attn: x1 = LN(X + attn(X)) ----
    GEMM(1, 1, X, D, Wh[0], DH, nullptr, qb, D, nullptr, 0, 0, 1.f,
         Bn * T, DH, DH, H, H, 0, DH, 0, DH * DH, 0, DH);
    GEMM(1, 1, X, D, Wh[1], DH, nullptr, kb, D, nullptr, 0, 0, 1.f,
         Bn * T, DH, DH, H, H, 0, DH, 0, DH * DH, 0, DH);
    GEMM(1, 1, X, D, Wh[2], DH, nullptr, vb, D, nullptr, 0, 0, 1.f,
         Bn * T, DH, DH, H, H, 0, DH, 0, DH * DH, 0, DH);
    k_transpose<<<dim3(T / 32, DH / 32, Bn * H), dim3(256), 0, stream>>>(vb, tmpB);
    k_attn<1><<<dim3(T / 64, H, Bn), dim3(256), 0, stream>>>(qb, kb, tmpB, vb, T, 0.0625f);
    k_addln<1, 0><<<dim3(Bn * T), dim3(256), 0, stream>>>(X, vb, ln[0], ln[1], nullptr, x1b);

    // ---- 2) encoder self-attn: c1 = LN(ctx + attn(ctx)) ----
    GEMM(1, 1, ctx, D, Wh[6], DH, nullptr, qb, D, nullptr, 0, 0, 1.f,
         Bn * T, DH, DH, H, H, 0, DH, 0, DH * DH, 0, DH);
    GEMM(1, 1, ctx, D, Wh[7], DH, nullptr, kb, D, nullptr, 0, 0, 1.f,
         Bn * T, DH, DH, H, H, 0, DH, 0, DH * DH, 0, DH);
    GEMM(1, 1, ctx, D, Wh[8], DH, nullptr, vb, D, nullptr, 0, 0, 1.f,
         Bn * T, DH, DH, H, H, 0, DH, 0, DH * DH, 0, DH);
    k_transpose<<<dim3(T / 32, DH / 32, Bn * H), dim3(256), 0, stream>>>(vb, tmpB);
    k_attn<0><<<dim3(T / 64, H, Bn), dim3(256), 0, stream>>>(qb, kb, tmpB, vb, T, 0.0625f);
    k_addln<1, 0><<<dim3(Bn * T), dim3(256), 0, stream>>>(ctx, vb, ln[6], ln[7], nullptr, t2b);

    // ---- 3) encoder FFN (k-chunked): c = LN(c1 + ffn(c1)) -> outC ----
    for (int c = 0; c < 4; c++) {
        if (wcast) {
            GEMM(0, 0, t2b, D, w1eb + (long)c * 1024 * 1024, 1024, nullptr, hb, 1024,
                 enc_b1 + c * 1024, 1, 0, 1.f, Bn * T, 1024, 1024, 1, 1, 0, 0, 0, 0, 0, 0);
            GEMM(0, 0, hb, 1024, w2eb + c * 1024, 4096, tmpF, nullptr, 1024,
                 c == 0 ? enc_b2 : nullptr, 0, c > 0, 1.f,
                 Bn * T, 1024, 1024, 1, 1, 0, 0, 0, 0, 0, 0);
        } else {
            GEMM(0, 1, t2b, D, enc_w1 + (long)c * 1024 * 1024, 1024, nullptr, hb, 1024,
                 enc_b1 + c * 1024, 1, 0, 1.f, Bn * T, 1024, 1024, 1, 1, 0, 0, 0, 0, 0, 0);
            GEMM(0, 1, hb, 1024, enc_w2 + c * 1024, 4096, tmpF, nullptr, 1024,
                 c == 0 ? enc_b2 : nullptr, 0, c > 0, 1.f,
                 Bn * T, 1024, 1024, 1, 1, 0, 0, 0, 0, 0, 0);
        }
    }
    k_addln<0, 1><<<dim3(Bn * T), dim3(256), 0, stream>>>(t2b, tmpF, ln[8], ln[9], outC, nullptr);

    // ---- 4) cross attention (no softmax): o = q (K^T V)^T / 16 ----
    GEMM(0, 1, x1b, D, Wh[3], DH, nullptr, qb, D, nullptr, 0, 0, 1.f,
         Bn * T, DH, DH, H, H, 0, DH, 0, DH * DH, 0, DH);
    GEMM(1, 1, outC, D, Wh[4], DH, nullptr, kb, D, nullptr, 0, 0, 1.f,
         Bn * T, DH, DH, H, H, 0, DH, 0, DH * DH, 0, DH);
    k_transpose<<<dim3(T / 32, DH / 32, Bn * H), dim3(256), 0, stream>>>(kb, Kt);
    GEMM(1, 1, outC, D, Wh[5], DH, nullptr, kb, D, nullptr, 0, 0, 1.f,
         Bn * T, DH, DH, H, H, 0, DH, 0, DH * DH, 0, DH);
    k_transpose<<<dim3(T / 32, DH / 32, Bn * H), dim3(256), 0, stream>>>(kb, Vt);
    // Nm[f][e] = sum_t V[t][f] K[t][e]  per (b,h)
    GEMM(0, 0, Vt, T, Kt, T, nullptr, Nm, DH, nullptr, 0, 0, 1.f,
         DH, DH, T, Bn * H, Bn * H, 0, (long)DH * T, 0, (long)DH * T, 0, DH * DH);
    // o[t][f] = (1/16) sum_e q[t][e] Nm[f][e]  per (b,h)
    GEMM(0, 0, qb, D, Nm, DH, nullptr, tmpB, D, nullptr, 0, 0, 0.0625f,
         T, DH, DH, Bn * H, H, (long)T * D, DH, (long)H * DH * DH, DH * DH,
         (long)T * D, DH);
    k_addln<0, 0><<<dim3(Bn * T), dim3(256), 0, stream>>>(x1b, tmpB, ln[2], ln[3], nullptr, t2b);

    // ---- 5) decoder FFN (k-chunked): out = LN(x2 + ffn(x2)) -> outY ----
    for (int c = 0; c < 4; c++) {
        if (wcast) {
            GEMM(0, 0, t2b, D, w1db + (long)c * 1024 * 1024, 1024, nullptr, hb, 1024,
                 dec_b1 + c * 1024, 1, 0, 1.f, Bn * T, 1024, 1024, 1, 1, 0, 0, 0, 0, 0, 0);
            GEMM(0, 0, hb, 1024, w2db + c * 1024, 4096, tmpF, nullptr, 1024,
                 c == 0 ? dec_b2 : nullptr, 0, c > 0, 1.f,
                 Bn * T, 1024, 1024, 1, 1, 0, 0, 0, 0, 0, 0);
        } else {
            GEMM(0, 1, t2b, D, dec_w1 + (long)c * 1024 * 1024, 1024, nullptr, hb, 1024,
                 dec_b1 + c * 1024, 1, 0, 1.f, Bn * T, 1024, 1024, 1, 1, 0, 0, 0, 0, 0, 0);
            GEMM(0, 1, hb, 1024, dec_w2 + c * 1024, 4096, tmpF, nullptr, 1024,
                 c == 0 ? dec_b2 : nullptr, 0, c > 0, 1.f,
                 Bn * T, 1024, 1024, 1, 1, 0, 0, 0, 0, 0, 0);
        }
    }
    k_addln<0, 1><<<dim3(Bn * T), dim3(256), 0, stream>>>(t2b, tmpF, ln[4], ln[5], outY, nullptr);
}